// Round 5
// baseline (1009.531 us; speedup 1.0000x reference)
//
#include <hip/hip_runtime.h>

// ---------------- problem constants ----------------
constexpr int NG = 64;
constexpr int NN = 8192;
constexpr int HH = 64;
constexpr int NE = 262144;
constexpr int MM = NG * NN;          // 524288 rows
constexpr float LAM = 0.2f;
constexpr float EPS = 1e-5f;

// ---------------- ws layout (bytes) ----------------
constexpr size_t WO_STATS = 0;                    // 16384 floats (64KB), zeroed
constexpr size_t WO_INTS  = 0x10000;              // pcnt[64], pgene[128], zeroed
constexpr size_t WO_DEG   = 0x11000;              // 8192 f, zeroed
constexpr size_t WO_G     = 0x19000;              // 4096 f (Gram), zeroed
constexpr size_t WO_AGG   = 0x1D000;              // 524288 f, zeroed
constexpr size_t ZERO_BYTES = WO_AGG + (size_t)NN * 64 * 4;   // 0x21D000
constexpr size_t WO_CG    = ZERO_BYTES;           // NG*64 f
constexpr size_t WO_W2T   = WO_CG   + 4096 * 4;   // 8192 f
constexpr size_t WO_BASER = WO_W2T  + 8192 * 4;   // N*64 f
constexpr size_t WO_BASE  = WO_BASER + (size_t)NN * 64 * 4;
constexpr size_t WO_XG    = WO_BASE  + (size_t)NN * 64 * 4;
constexpr size_t WO_PGE   = WO_XG    + (size_t)NN * 64 * 4;
constexpr size_t WO_Y3    = WO_PGE   + (size_t)NN * 64 * 4;
constexpr size_t WO_Y2    = WO_Y3    + (size_t)MM * 4;

// stats sub-offsets (float indices)
constexpr int SF_SUME = 0, SF_SUME2 = 64, SF_SUMB = 128, SF_SUMB2 = 192;
constexpr int SF_SUMC = 256, SF_SUMC2 = 320, SF_CORRV = 384, SF_CORRV2 = 448;
constexpr int SF_SUMU = 512, SF_SUMU2 = 576, SF_SUMT = 640;
constexpr int SF_MEAN3 = 704, SF_VAR3 = 832;       // 128 each
constexpr int SF_A4 = 960, SF_BE4 = 1024, SF_BN5 = 1088;
constexpr int SF_SY2 = 1152, SF_SY2Q = 5248;       // 64 banks x 64 ch
constexpr int SF_SY3 = 9344;                       // 1024 banks x 2

#define DEVINL __device__ __forceinline__

DEVINL float wredsum(float v) {
#pragma unroll
  for (int o = 32; o; o >>= 1) v += __shfl_xor(v, o);
  return v;
}

// BN1 (bn_pbt) params from analytic sums.  v = base_n + c_g (+ rare w)
DEVINL void bn1_params(const float* st, const float* g, const float* b, int h,
                       float& a, float& be) {
  float sB = st[SF_SUMB + h], sB2 = st[SF_SUMB2 + h];
  float sC = st[SF_SUMC + h], sC2 = st[SF_SUMC2 + h];
  float mean = (NG * sB + NN * sC + st[SF_CORRV + h]) * (1.0f / MM);
  float e2 = (NG * sB2 + 2.0f * sB * sC + NN * sC2 + st[SF_CORRV2 + h]) * (1.0f / MM);
  float rs = rsqrtf(e2 - mean * mean + EPS);
  a = g[h] * rs;
  be = b[h] - mean * g[h] * rs;
}

// BN2 (bn_pb) params from direct sums of u
DEVINL void bn2_params(const float* st, const float* g, const float* b, int h,
                       float& a, float& be) {
  float m = st[SF_SUMU + h] * (1.0f / MM);
  float var = st[SF_SUMU2 + h] * (1.0f / MM) - m * m;
  float rs = rsqrtf(var + EPS);
  a = g[h] * rs;
  be = b[h] - m * g[h] * rs;
}

// K1: renorm both embeddings (max_norm=1); accumulate gene-emb channel sums
__global__ void k_renorm(const float* __restrict__ ge, const float* __restrict__ pe,
                         float* __restrict__ baseR, float* __restrict__ xg,
                         float* __restrict__ st) {
  __shared__ float red[128];
  if (threadIdx.x < 128) red[threadIdx.x] = 0.f;
  __syncthreads();
  int lane = threadIdx.x & 63;
  int wid = (blockIdx.x * blockDim.x + threadIdx.x) >> 6;
  int nw = (gridDim.x * blockDim.x) >> 6;
  float s1 = 0.f, s2 = 0.f;
  for (int r = wid; r < 2 * NN; r += nw) {
    int gene = r < NN;
    int n = gene ? r : r - NN;
    const float* src = gene ? ge : pe;
    float v = src[n * 64 + lane];
    float sq = wredsum(v * v);
    float nrm = sqrtf(sq);
    float sc = nrm > 1.0f ? 1.0f / (nrm + 1e-7f) : 1.0f;
    v *= sc;
    if (gene) { baseR[n * 64 + lane] = v; s1 += v; s2 += v * v; }
    else      { xg[n * 64 + lane] = v; }
  }
  atomicAdd(&red[lane], s1);
  atomicAdd(&red[64 + lane], s2);
  __syncthreads();
  if (threadIdx.x < 64) {
    atomicAdd(&st[SF_SUME + threadIdx.x], red[threadIdx.x]);
    atomicAdd(&st[SF_SUME2 + threadIdx.x], red[64 + threadIdx.x]);
  }
}

// K0b: transpose rw2_W [64][128] -> W2T [128][64]
__global__ void k_w2t(const float* __restrict__ W2, float* __restrict__ W2T) {
  int i = blockIdx.x * blockDim.x + threadIdx.x;
  if (i < 64 * 128) {
    int r = i >> 7, c = i & 127;
    W2T[c * 64 + r] = W2[i];
  }
}

// K2: base_n = relu(BN_emb(renormed gene emb)); accumulate sumB, sumB2
__global__ void k_base(const float* __restrict__ baseR, const float* __restrict__ g,
                       const float* __restrict__ b, float* __restrict__ base,
                       float* __restrict__ st) {
  __shared__ float red[128];
  if (threadIdx.x < 128) red[threadIdx.x] = 0.f;
  __syncthreads();
  int h = threadIdx.x & 63;
  float m = st[SF_SUME + h] * (1.0f / NN);
  float var = st[SF_SUME2 + h] * (1.0f / NN) - m * m;
  float rs = rsqrtf(var + EPS);
  float a = g[h] * rs, be = b[h] - m * g[h] * rs;
  float s1 = 0.f, s2 = 0.f;
  int stride = gridDim.x * blockDim.x;
  for (int i = blockIdx.x * blockDim.x + threadIdx.x; i < NN * 64; i += stride) {
    float v = fmaxf(baseR[i] * a + be, 0.f);
    base[i] = v; s1 += v; s2 += v * v;
  }
  atomicAdd(&red[h], s1);
  atomicAdd(&red[64 + h], s2);
  __syncthreads();
  if (threadIdx.x < 64) {
    atomicAdd(&st[SF_SUMB + threadIdx.x], red[threadIdx.x]);
    atomicAdd(&st[SF_SUMB2 + threadIdx.x], red[64 + threadIdx.x]);
  }
}

// K3: degree (segment_sum of w by col, + self loops)
__global__ void k_deg(const int* __restrict__ ei, const float* __restrict__ ew,
                      float* __restrict__ deg) {
  int i = blockIdx.x * blockDim.x + threadIdx.x;
  if (i < NE) atomicAdd(&deg[ei[NE + i]], ew[i]);
  else if (i < NE + NN) atomicAdd(&deg[i - NE], 1.0f);
}

// K4: agg[col] += dinv[row]*w*dinv[col] * xg[row]  (one wave per edge)
__global__ void k_agg(const int* __restrict__ ei, const float* __restrict__ ew,
                      const float* __restrict__ deg, const float* __restrict__ xg,
                      float* __restrict__ agg) {
  int w = (blockIdx.x * blockDim.x + threadIdx.x) >> 6;
  int lane = threadIdx.x & 63;
  if (w < NE) {
    int r = ei[w], c = ei[NE + w];
    float dr = deg[r], dc = deg[c];
    float nrm = ew[w] * (dr > 0.f ? rsqrtf(dr) : 0.f) * (dc > 0.f ? rsqrtf(dc) : 0.f);
    atomicAdd(&agg[c * 64 + lane], nrm * xg[r * 64 + lane]);
  } else if (w < NE + NN) {
    int n = w - NE;
    float d = deg[n];
    float nrm = d > 0.f ? 1.0f / d : 0.f;   // dinv * 1 * dinv
    atomicAdd(&agg[n * 64 + lane], nrm * xg[n * 64 + lane]);
  }
}

// K5: pge = agg @ sgW.T + sgb  (lane j holds W row j in regs; agg via shfl)
__global__ void k_pge(const float* __restrict__ agg, const float* __restrict__ W,
                      const float* __restrict__ bb, float* __restrict__ pge) {
  int lane = threadIdx.x & 63;
  int wid = (blockIdx.x * blockDim.x + threadIdx.x) >> 6;
  int nw = (gridDim.x * blockDim.x) >> 6;
  float wr[64];
#pragma unroll
  for (int k4 = 0; k4 < 16; k4++) {
    float4 t = *(const float4*)&W[lane * 64 + k4 * 4];
    wr[k4 * 4] = t.x; wr[k4 * 4 + 1] = t.y; wr[k4 * 4 + 2] = t.z; wr[k4 * 4 + 3] = t.w;
  }
  float bj = bb[lane];
  for (int n = wid; n < NN; n += nw) {
    float av = agg[n * 64 + lane];
    float acc = bj;
#pragma unroll
    for (int k = 0; k < 64; k++) acc += __shfl(av, k) * wr[k];
    pge[n * 64 + lane] = acc;
  }
}

// K6: find perturbed genes from x[:,1]
__global__ void k_extract(const float* __restrict__ x, int* __restrict__ pcnt,
                          int* __restrict__ pgene) {
  int r = blockIdx.x * blockDim.x + threadIdx.x;
  if (r < MM) {
    float v = x[(size_t)2 * r + 1];
    if (v != 0.0f) {
      int g = r >> 13;
      int slot = atomicAdd(&pcnt[g], 1);
      if (slot < 2) pgene[g * 2 + slot] = r & (NN - 1);
    }
  }
}

// K7: c_g = LAM * sum(pge[pert]) + pert_b; accumulate sumC, sumC2
__global__ void k_cg(const float* __restrict__ pge, const float* __restrict__ pb,
                     const int* __restrict__ pcnt, const int* __restrict__ pgene,
                     float* __restrict__ cg, float* __restrict__ st) {
  int g = blockIdx.x, h = threadIdx.x;
  float c = pb[h];
  int cnt = pcnt[g]; if (cnt > 2) cnt = 2;
  for (int i = 0; i < cnt; i++) c += LAM * pge[pgene[g * 2 + i] * 64 + h];
  cg[g * 64 + h] = c;
  atomicAdd(&st[SF_SUMC + h], c);
  atomicAdd(&st[SF_SUMC2 + h], c * c);
}

// K7b: BN1 corrections for perturbed rows (single block)
__global__ void k_corr1(const float* __restrict__ base, const float* __restrict__ cg,
                        const float* __restrict__ pw, const int* __restrict__ pcnt,
                        const int* __restrict__ pgene, float* __restrict__ st) {
  int h = threadIdx.x;
  float w = pw[h];
  float c1 = 0.f, c2 = 0.f;
  for (int g = 0; g < NG; g++) {
    int cnt = pcnt[g]; if (cnt > 2) cnt = 2;
    for (int i = 0; i < cnt; i++) {
      float v0 = base[pgene[g * 2 + i] * 64 + h] + cg[g * 64 + h];
      c1 += w;
      c2 += 2.f * v0 * w + w * w;
    }
  }
  st[SF_CORRV + h] = c1;
  st[SF_CORRV2 + h] = c2;
}

// K8: BN2 stats: u = relu(BN1(base_n + c_g)) summed over all (g,n)
__global__ void k_ustats(const float* __restrict__ base, const float* __restrict__ cg,
                         const float* __restrict__ g1, const float* __restrict__ b1,
                         float* __restrict__ st) {
  __shared__ float red[128];
  if (threadIdx.x < 128) red[threadIdx.x] = 0.f;
  __syncthreads();
  int h = threadIdx.x & 63;
  int g = blockIdx.x >> 3;
  int n0 = (blockIdx.x & 7) * 1024;
  float a1, be1; bn1_params(st, g1, b1, h, a1, be1);
  float ch = cg[g * 64 + h];
  float s1 = 0.f, s2 = 0.f;
  for (int r = n0 + (threadIdx.x >> 6); r < n0 + 1024; r += 4) {
    float u = fmaxf(a1 * (base[r * 64 + h] + ch) + be1, 0.f);
    s1 += u; s2 += u * u;
  }
  atomicAdd(&red[h], s1);
  atomicAdd(&red[64 + h], s2);
  __syncthreads();
  if (threadIdx.x < 64) {
    atomicAdd(&st[SF_SUMU + threadIdx.x], red[threadIdx.x]);
    atomicAdd(&st[SF_SUMU2 + threadIdx.x], red[64 + threadIdx.x]);
  }
}

// K8b: BN2 stat corrections for perturbed rows (single block)
__global__ void k_ucorr(const float* __restrict__ base, const float* __restrict__ cg,
                        const float* __restrict__ pw, const int* __restrict__ pcnt,
                        const int* __restrict__ pgene, const float* __restrict__ g1,
                        const float* __restrict__ b1, float* __restrict__ st) {
  int h = threadIdx.x;
  float a1, be1; bn1_params(st, g1, b1, h, a1, be1);
  float w = pw[h];
  float d1 = 0.f, d2 = 0.f;
  for (int g = 0; g < NG; g++) {
    int cnt = pcnt[g]; if (cnt > 2) cnt = 2;
    for (int i = 0; i < cnt; i++) {
      float v0 = base[pgene[g * 2 + i] * 64 + h] + cg[g * 64 + h];
      float u0 = fmaxf(a1 * v0 + be1, 0.f);
      float uw = fmaxf(a1 * (v0 + w) + be1, 0.f);
      d1 += uw - u0;
      d2 += uw * uw - u0 * u0;
    }
  }
  st[SF_SUMU + h] += d1;
  st[SF_SUMU2 + h] += d2;
}

// K9: Gram of t = relu(BN2(relu(BN1(base+c)))), plus sumT
__global__ void k_gram(const float* __restrict__ base, const float* __restrict__ cg,
                       const float* __restrict__ g1, const float* __restrict__ b1,
                       const float* __restrict__ g2, const float* __restrict__ b2,
                       float* __restrict__ G, float* __restrict__ st) {
  __shared__ __align__(16) float tS[16][68];
  __shared__ float red[128];
  if (threadIdx.x < 128) red[threadIdx.x] = 0.f;
  int h = threadIdx.x & 63;
  int g = blockIdx.x >> 3;
  int n0 = (blockIdx.x & 7) * 1024;
  float a1, be1, a2, be2;
  bn1_params(st, g1, b1, h, a1, be1);
  bn2_params(st, g2, b2, h, a2, be2);
  float ch = cg[g * 64 + h];
  int i0 = (threadIdx.x >> 4) * 4;
  int j0 = (threadIdx.x & 15) * 4;
  float acc[4][4] = {};
  float sT = 0.f;
  for (int nb = 0; nb < 1024; nb += 16) {
    __syncthreads();
#pragma unroll
    for (int it = 0; it < 4; it++) {
      int r = it * 4 + (threadIdx.x >> 6);
      float v = base[(n0 + nb + r) * 64 + h] + ch;
      float t = fmaxf(a2 * fmaxf(a1 * v + be1, 0.f) + be2, 0.f);
      tS[r][h] = t;
      sT += t;
    }
    __syncthreads();
#pragma unroll
    for (int r = 0; r < 16; r++) {
      float4 a4 = *(const float4*)&tS[r][i0];
      float4 b4 = *(const float4*)&tS[r][j0];
      float ai[4] = {a4.x, a4.y, a4.z, a4.w};
      float bj[4] = {b4.x, b4.y, b4.z, b4.w};
#pragma unroll
      for (int a = 0; a < 4; a++)
#pragma unroll
        for (int b = 0; b < 4; b++) acc[a][b] += ai[a] * bj[b];
    }
  }
#pragma unroll
  for (int a = 0; a < 4; a++)
#pragma unroll
    for (int b = 0; b < 4; b++)
      atomicAdd(&G[(i0 + a) * 64 + j0 + b], acc[a][b]);
  atomicAdd(&red[h], sT);
  __syncthreads();
  if (threadIdx.x < 64) atomicAdd(&st[SF_SUMT + threadIdx.x], red[threadIdx.x]);
}

// K9b: Gram + sumT corrections for perturbed rows (single block, 256 thr)
__global__ void k_gramcorr(const float* __restrict__ base, const float* __restrict__ cg,
                           const float* __restrict__ pw, const int* __restrict__ pcnt,
                           const int* __restrict__ pgene,
                           const float* __restrict__ g1, const float* __restrict__ b1,
                           const float* __restrict__ g2, const float* __restrict__ b2,
                           float* __restrict__ G, float* __restrict__ st) {
  __shared__ float t0S[64], twS[64];
  int tid = threadIdx.x;
  int h = tid & 63;
  float a1, be1, a2, be2;
  bn1_params(st, g1, b1, h, a1, be1);
  bn2_params(st, g2, b2, h, a2, be2);
  int i0 = (tid >> 4) * 4;
  int j0 = (tid & 15) * 4;
  float accD[4][4] = {};
  float dT = 0.f;
  for (int g = 0; g < NG; g++) {
    int cnt = pcnt[g]; if (cnt > 2) cnt = 2;
    for (int i = 0; i < cnt; i++) {
      __syncthreads();
      if (tid < 64) {
        float v0 = base[pgene[g * 2 + i] * 64 + tid] + cg[g * 64 + tid];
        float t0 = fmaxf(a2 * fmaxf(a1 * v0 + be1, 0.f) + be2, 0.f);
        float tw = fmaxf(a2 * fmaxf(a1 * (v0 + pw[tid]) + be1, 0.f) + be2, 0.f);
        t0S[tid] = t0; twS[tid] = tw;
        dT += tw - t0;
      }
      __syncthreads();
#pragma unroll
      for (int a = 0; a < 4; a++)
#pragma unroll
        for (int b = 0; b < 4; b++)
          accD[a][b] += twS[i0 + a] * twS[j0 + b] - t0S[i0 + a] * t0S[j0 + b];
    }
  }
#pragma unroll
  for (int a = 0; a < 4; a++)
#pragma unroll
    for (int b = 0; b < 4; b++)
      G[(i0 + a) * 64 + j0 + b] += accD[a][b];
  if (tid < 64) st[SF_SUMT + tid] += dT;
}

// K9c: BN3 stats from Gram: y1_j = w_j.t + b1_j
__global__ void k_bn3(const float* __restrict__ W1, const float* __restrict__ b1v,
                      const float* __restrict__ G, float* __restrict__ st) {
  int j = blockIdx.x, h = threadIdx.x;
  float wjh = W1[j * 64 + h];
  float inner = 0.f;
  for (int l = 0; l < 64; l++) inner += G[h * 64 + l] * W1[j * 64 + l];
  float q = wredsum(wjh * inner);
  float s = wredsum(wjh * st[SF_SUMT + h]);
  if (h == 0) {
    float bj = b1v[j];
    float mu = s * (1.0f / MM) + bj;
    float e2 = q * (1.0f / MM) + 2.0f * bj * s * (1.0f / MM) + bj * bj;
    st[SF_MEAN3 + j] = mu;
    st[SF_VAR3 + j] = e2 - mu * mu;
  }
}

// K10: the big fused MLP pass.
// MODE 0: store y2 + BN4 stat sums.  MODE 1: BN4 stat sums only.
// MODE 2: recompute, apply BN4, produce y3 + BN5 stat sums.
template <int MODE>
__launch_bounds__(128)
__global__ void k_mlp(const float* __restrict__ x, const float* __restrict__ base,
                      const float* __restrict__ cg, const float* __restrict__ pw,
                      const float* __restrict__ g1, const float* __restrict__ b1,
                      const float* __restrict__ g2, const float* __restrict__ b2,
                      const float* __restrict__ W1, const float* __restrict__ b1v,
                      const float* __restrict__ g3, const float* __restrict__ b3,
                      const float* __restrict__ W2T, const float* __restrict__ b2v,
                      const float* __restrict__ w3, const float* __restrict__ b3v,
                      float* __restrict__ st, float* __restrict__ y2out,
                      float* __restrict__ y3out) {
  __shared__ __align__(16) float tT[64][68];    // [k][row]
  __shared__ __align__(16) float h1T[128][68];  // [j][row]
  __shared__ float cS[64];
  __shared__ float x1S[64];
  __shared__ float red[128];
  int tid = threadIdx.x;
  int g = blockIdx.x >> 7;
  int n0 = (blockIdx.x & 127) * 64;
  int k = tid & 63;
  float a1, be1, a2, be2;
  bn1_params(st, g1, b1, k, a1, be1);
  bn2_params(st, g2, b2, k, a2, be2);
  if (tid < 64) cS[tid] = cg[g * 64 + tid];
  else {
    int r = tid - 64;
    x1S[r] = x[((size_t)(g * NN + n0 + r)) * 2 + 1];
  }
  if (tid < 128) red[tid] = 0.f;
  __syncthreads();
  float pwk = pw[k];
  float chk = cS[k];
  // fill t (transposed): thread covers 32 rows at its channel k
#pragma unroll
  for (int it = 0; it < 32; it++) {
    int r = it * 2 + (tid >> 6);
    float v = base[(n0 + r) * 64 + k] + chk + x1S[r] * pwk;
    float t = fmaxf(a2 * fmaxf(a1 * v + be1, 0.f) + be2, 0.f);
    tT[k][r] = t;
  }
  __syncthreads();

  // ---- GEMM1: y1[64 rows][128 j], thread tile 8x8 ----
  int rg = tid >> 4;        // 0..7
  int r0 = rg * 8;
  int j0 = (tid & 15) * 8;
  float acc[8][8] = {};
  for (int kc = 0; kc < 64; kc += 4) {
    float w[8][4];
#pragma unroll
    for (int jj = 0; jj < 8; jj++) {
      float4 t4 = *(const float4*)&W1[(j0 + jj) * 64 + kc];
      w[jj][0] = t4.x; w[jj][1] = t4.y; w[jj][2] = t4.z; w[jj][3] = t4.w;
    }
#pragma unroll
    for (int kk = 0; kk < 4; kk++) {
      float4 ta = *(const float4*)&tT[kc + kk][r0];
      float4 tb = *(const float4*)&tT[kc + kk][r0 + 4];
      float tv[8] = {ta.x, ta.y, ta.z, ta.w, tb.x, tb.y, tb.z, tb.w};
#pragma unroll
      for (int rr = 0; rr < 8; rr++)
#pragma unroll
        for (int jj = 0; jj < 8; jj++)
          acc[rr][jj] += tv[rr] * w[jj][kk];
    }
  }
  // h1 = relu(BN3(y1 + b1)) -> LDS transposed
#pragma unroll
  for (int jj = 0; jj < 8; jj++) {
    int j = j0 + jj;
    float mu = st[SF_MEAN3 + j], va = st[SF_VAR3 + j];
    float rs = rsqrtf(va + EPS);
    float a3 = g3[j] * rs, be3 = b3[j] - mu * a3;
    float bj = b1v[j];
    float hv[8];
#pragma unroll
    for (int rr = 0; rr < 8; rr++)
      hv[rr] = fmaxf(a3 * (acc[rr][jj] + bj) + be3, 0.f);
    *(float4*)&h1T[j][r0]     = make_float4(hv[0], hv[1], hv[2], hv[3]);
    *(float4*)&h1T[j][r0 + 4] = make_float4(hv[4], hv[5], hv[6], hv[7]);
  }
  __syncthreads();

  // ---- GEMM2: y2[64 rows][64 i], thread tile 8x4 ----
  int i0 = (tid & 15) * 4;
  float acc2[8][4] = {};
  for (int jc = 0; jc < 128; jc += 4) {
    float wv[4][4];
#pragma unroll
    for (int jj = 0; jj < 4; jj++) {
      float4 t4 = *(const float4*)&W2T[(jc + jj) * 64 + i0];
      wv[jj][0] = t4.x; wv[jj][1] = t4.y; wv[jj][2] = t4.z; wv[jj][3] = t4.w;
    }
#pragma unroll
    for (int jj = 0; jj < 4; jj++) {
      float4 ha = *(const float4*)&h1T[jc + jj][r0];
      float4 hb = *(const float4*)&h1T[jc + jj][r0 + 4];
      float hv[8] = {ha.x, ha.y, ha.z, ha.w, hb.x, hb.y, hb.z, hb.w};
#pragma unroll
      for (int rr = 0; rr < 8; rr++)
#pragma unroll
        for (int ii = 0; ii < 4; ii++)
          acc2[rr][ii] += hv[rr] * wv[jj][ii];
    }
  }
  float bi[4];
#pragma unroll
  for (int ii = 0; ii < 4; ii++) bi[ii] = b2v[i0 + ii];
#pragma unroll
  for (int rr = 0; rr < 8; rr++)
#pragma unroll
    for (int ii = 0; ii < 4; ii++) acc2[rr][ii] += bi[ii];

  if (MODE == 0) {
#pragma unroll
    for (int rr = 0; rr < 8; rr++) {
      size_t row = (size_t)(g * NN + n0 + r0 + rr);
      *(float4*)&y2out[row * 64 + i0] =
          make_float4(acc2[rr][0], acc2[rr][1], acc2[rr][2], acc2[rr][3]);
    }
  }
  if (MODE <= 1) {
    float s1[4] = {}, s2[4] = {};
#pragma unroll
    for (int rr = 0; rr < 8; rr++)
#pragma unroll
      for (int ii = 0; ii < 4; ii++) {
        s1[ii] += acc2[rr][ii];
        s2[ii] += acc2[rr][ii] * acc2[rr][ii];
      }
#pragma unroll
    for (int ii = 0; ii < 4; ii++) {
      atomicAdd(&red[i0 + ii], s1[ii]);
      atomicAdd(&red[64 + i0 + ii], s2[ii]);
    }
    __syncthreads();
    if (tid < 64) {
      int bank = blockIdx.x & 63;
      atomicAdd(&st[SF_SY2 + bank * 64 + tid], red[tid]);
      atomicAdd(&st[SF_SY2Q + bank * 64 + tid], red[64 + tid]);
    }
  }
  if (MODE == 2) {
    float a4v[4], be4v[4], w3v[4];
#pragma unroll
    for (int ii = 0; ii < 4; ii++) {
      a4v[ii] = st[SF_A4 + i0 + ii];
      be4v[ii] = st[SF_BE4 + i0 + ii];
      w3v[ii] = w3[i0 + ii];
    }
#pragma unroll
    for (int rr = 0; rr < 8; rr++) {
      float part = 0.f;
#pragma unroll
      for (int ii = 0; ii < 4; ii++) {
        float h2 = fmaxf(a4v[ii] * acc2[rr][ii] + be4v[ii], 0.f);
        part += w3v[ii] * h2;
      }
      atomicAdd(&red[r0 + rr], part);
    }
    __syncthreads();
    if (tid < 64) {
      float yv = red[tid] + b3v[0];
      y3out[(size_t)(g * NN + n0 + tid)] = yv;
      float q1 = wredsum(yv);
      float q2 = wredsum(yv * yv);
      if (tid == 0) {
        int bank = blockIdx.x & 1023;
        atomicAdd(&st[SF_SY3 + bank * 2], q1);
        atomicAdd(&st[SF_SY3 + bank * 2 + 1], q2);
      }
    }
  }
}

// K11: finalize BN4 params from banked sums
__global__ void k_bn4fin(const float* __restrict__ g4, const float* __restrict__ b4,
                         float* __restrict__ st) {
  int h = threadIdx.x;
  float s1 = 0.f, s2 = 0.f;
  for (int b = 0; b < 64; b++) {
    s1 += st[SF_SY2 + b * 64 + h];
    s2 += st[SF_SY2Q + b * 64 + h];
  }
  float m = s1 * (1.0f / MM);
  float var = s2 * (1.0f / MM) - m * m;
  float rs = rsqrtf(var + EPS);
  st[SF_A4 + h] = g4[h] * rs;
  st[SF_BE4 + h] = b4[h] - m * g4[h] * rs;
}

// K12 (store path): read y2, apply BN4+relu, dot w3 -> y3 + BN5 sums
__global__ void k_fin_read(const float* __restrict__ y2g, const float* __restrict__ w3,
                           const float* __restrict__ b3v, float* __restrict__ st,
                           float* __restrict__ y3) {
  int lane = threadIdx.x & 63;
  float a4 = st[SF_A4 + lane], be4 = st[SF_BE4 + lane], w = w3[lane];
  int wid = (blockIdx.x * blockDim.x + threadIdx.x) >> 6;
  int nw = (gridDim.x * blockDim.x) >> 6;
  float q1 = 0.f, q2 = 0.f;
  for (int r = wid; r < MM; r += nw) {
    float v = y2g[(size_t)r * 64 + lane];
    float p = wredsum(w * fmaxf(a4 * v + be4, 0.f));
    if (lane == 0) {
      float yv = p + b3v[0];
      y3[r] = yv;
      q1 += yv; q2 += yv * yv;
    }
  }
  if (lane == 0) {
    int bank = (blockIdx.x * 4 + (threadIdx.x >> 6)) & 1023;
    atomicAdd(&st[SF_SY3 + bank * 2], q1);
    atomicAdd(&st[SF_SY3 + bank * 2 + 1], q2);
  }
}

// K12b: finalize BN5
__global__ void k_bn5fin(const float* __restrict__ g5, const float* __restrict__ b5,
                         float* __restrict__ st) {
  int t = threadIdx.x;
  float s1 = 0.f, s2 = 0.f;
  for (int b = t; b < 1024; b += 64) {
    s1 += st[SF_SY3 + b * 2];
    s2 += st[SF_SY3 + b * 2 + 1];
  }
  s1 = wredsum(s1);
  s2 = wredsum(s2);
  if (t == 0) {
    float m = s1 * (1.0f / MM);
    float var = s2 * (1.0f / MM) - m * m;
    float rs = rsqrtf(var + EPS);
    st[SF_BN5] = g5[0] * rs;
    st[SF_BN5 + 1] = b5[0] - m * g5[0] * rs;
  }
}

// K13: out = BN5(y3) + x[:,0]
__global__ void k_out(const float* __restrict__ y3, const float* __restrict__ x,
                      const float* __restrict__ st, float* __restrict__ out) {
  int i = blockIdx.x * blockDim.x + threadIdx.x;
  float sc = st[SF_BN5], sh = st[SF_BN5 + 1];
  if (i < MM) out[i] = y3[i] * sc + sh + x[(size_t)i * 2];
}

extern "C" void kernel_launch(void* const* d_in, const int* in_sizes, int n_in,
                              void* d_out, int out_size, void* d_ws, size_t ws_size,
                              hipStream_t stream) {
  const float* x   = (const float*)d_in[0];
  const int*   ei  = (const int*)d_in[1];
  const float* ew  = (const float*)d_in[2];
  const float* ge  = (const float*)d_in[3];
  const float* pe  = (const float*)d_in[4];
  const float* pW  = (const float*)d_in[5];
  const float* pb  = (const float*)d_in[6];
  const float* sgW = (const float*)d_in[7];
  const float* sgb = (const float*)d_in[8];
  const float* beg = (const float*)d_in[9],  *beb = (const float*)d_in[10];
  const float* g1  = (const float*)d_in[11], *b1  = (const float*)d_in[12];
  const float* g2  = (const float*)d_in[13], *b2  = (const float*)d_in[14];
  const float* W1  = (const float*)d_in[15], *b1v = (const float*)d_in[16];
  const float* g3  = (const float*)d_in[17], *b3  = (const float*)d_in[18];
  const float* W2  = (const float*)d_in[19], *b2v = (const float*)d_in[20];
  const float* g4  = (const float*)d_in[21], *b4  = (const float*)d_in[22];
  const float* w3  = (const float*)d_in[23], *b3v = (const float*)d_in[24];
  const float* g5  = (const float*)d_in[25], *b5  = (const float*)d_in[26];
  float* out = (float*)d_out;
  char* ws = (char*)d_ws;
  float* st    = (float*)(ws + WO_STATS);
  int*   pcnt  = (int*)(ws + WO_INTS);
  int*   pgene = pcnt + 64;
  float* deg   = (float*)(ws + WO_DEG);
  float* G     = (float*)(ws + WO_G);
  float* agg   = (float*)(ws + WO_AGG);
  float* cgp   = (float*)(ws + WO_CG);
  float* W2T   = (float*)(ws + WO_W2T);
  float* baseR = (float*)(ws + WO_BASER);
  float* base  = (float*)(ws + WO_BASE);
  float* xg    = (float*)(ws + WO_XG);
  float* pge   = (float*)(ws + WO_PGE);
  float* y3    = (float*)(ws + WO_Y3);
  float* y2    = (float*)(ws + WO_Y2);
  bool store = ws_size >= WO_Y2 + (size_t)MM * 64 * 4;

  hipMemsetAsync(d_ws, 0, ZERO_BYTES, stream);
  hipLaunchKernelGGL(k_renorm, dim3(256), dim3(256), 0, stream, ge, pe, baseR, xg, st);
  hipLaunchKernelGGL(k_w2t, dim3(32), dim3(256), 0, stream, W2, W2T);
  hipLaunchKernelGGL(k_base, dim3(512), dim3(256), 0, stream, baseR, beg, beb, base, st);
  hipLaunchKernelGGL(k_deg, dim3((NE + NN + 255) / 256), dim3(256), 0, stream, ei, ew, deg);
  hipLaunchKernelGGL(k_agg, dim3((NE + NN) / 4), dim3(256), 0, stream, ei, ew, deg, xg, agg);
  hipLaunchKernelGGL(k_pge, dim3(512), dim3(256), 0, stream, agg, sgW, sgb, pge);
  hipLaunchKernelGGL(k_extract, dim3(MM / 256), dim3(256), 0, stream, x, pcnt, pgene);
  hipLaunchKernelGGL(k_cg, dim3(64), dim3(64), 0, stream, pge, pb, pcnt, pgene, cgp, st);
  hipLaunchKernelGGL(k_corr1, dim3(1), dim3(64), 0, stream, base, cgp, pW, pcnt, pgene, st);
  hipLaunchKernelGGL(k_ustats, dim3(512), dim3(256), 0, stream, base, cgp, g1, b1, st);
  hipLaunchKernelGGL(k_ucorr, dim3(1), dim3(64), 0, stream, base, cgp, pW, pcnt, pgene, g1, b1, st);
  hipLaunchKernelGGL(k_gram, dim3(512), dim3(256), 0, stream, base, cgp, g1, b1, g2, b2, G, st);
  hipLaunchKernelGGL(k_gramcorr, dim3(1), dim3(256), 0, stream, base, cgp, pW, pcnt, pgene,
                     g1, b1, g2, b2, G, st);
  hipLaunchKernelGGL(k_bn3, dim3(128), dim3(64), 0, stream, W1, b1v, G, st);
  if (store) {
    hipLaunchKernelGGL(k_mlp<0>, dim3(8192), dim3(128), 0, stream,
                       x, base, cgp, pW, g1, b1, g2, b2, W1, b1v, g3, b3, W2T, b2v,
                       w3, b3v, st, y2, y3);
    hipLaunchKernelGGL(k_bn4fin, dim3(1), dim3(64), 0, stream, g4, b4, st);
    hipLaunchKernelGGL(k_fin_read, dim3(4096), dim3(256), 0, stream, y2, w3, b3v, st, y3);
  } else {
    hipLaunchKernelGGL(k_mlp<1>, dim3(8192), dim3(128), 0, stream,
                       x, base, cgp, pW, g1, b1, g2, b2, W1, b1v, g3, b3, W2T, b2v,
                       w3, b3v, st, y2, y3);
    hipLaunchKernelGGL(k_bn4fin, dim3(1), dim3(64), 0, stream, g4, b4, st);
    hipLaunchKernelGGL(k_mlp<2>, dim3(8192), dim3(128), 0, stream,
                       x, base, cgp, pW, g1, b1, g2, b2, W1, b1v, g3, b3, W2T, b2v,
                       w3, b3v, st, y2, y3);
  }
  hipLaunchKernelGGL(k_bn5fin, dim3(1), dim3(64), 0, stream, g5, b5, st);
  hipLaunchKernelGGL(k_out, dim3(MM / 256), dim3(256), 0, stream, y3, x, st, out);
}

// Round 7
// 944.008 us; speedup vs baseline: 1.0694x; 1.0694x over previous
//
#include <hip/hip_runtime.h>

// ---------------- problem constants ----------------
constexpr int NG = 64;
constexpr int NN = 8192;
constexpr int HH = 64;
constexpr int NE = 262144;
constexpr int MM = NG * NN;          // 524288 rows
constexpr float LAM = 0.2f;
constexpr float EPS = 1e-5f;

// ---------------- ws layout (bytes) ----------------
constexpr size_t WO_STATS = 0;                    // 16384 floats (64KB), zeroed
constexpr size_t WO_INTS  = 0x10000;              // pcnt[64], pgene[128], zeroed
constexpr size_t WO_DEG   = 0x11000;              // 8192 f, zeroed
constexpr size_t WO_G     = 0x19000;              // 4096 f (Gram), zeroed
constexpr size_t WO_AGG   = 0x1D000;              // 524288 f, zeroed
constexpr size_t ZERO_BYTES = WO_AGG + (size_t)NN * 64 * 4;   // 0x21D000
constexpr size_t WO_CG    = ZERO_BYTES;           // NG*64 f
constexpr size_t WO_W2T   = WO_CG   + 4096 * 4;   // 8192 f
constexpr size_t WO_BASER = WO_W2T  + 8192 * 4;   // N*64 f
constexpr size_t WO_BASE  = WO_BASER + (size_t)NN * 64 * 4;
constexpr size_t WO_XG    = WO_BASE  + (size_t)NN * 64 * 4;
constexpr size_t WO_PGE   = WO_XG    + (size_t)NN * 64 * 4;
constexpr size_t WO_Y3    = WO_PGE   + (size_t)NN * 64 * 4;
constexpr size_t WO_Y2    = WO_Y3    + (size_t)MM * 4;

// stats sub-offsets (float indices)
constexpr int SF_SUME = 0, SF_SUME2 = 64, SF_SUMB = 128, SF_SUMB2 = 192;
constexpr int SF_SUMC = 256, SF_SUMC2 = 320, SF_CORRV = 384, SF_CORRV2 = 448;
constexpr int SF_SUMU = 512, SF_SUMU2 = 576, SF_SUMT = 640;
constexpr int SF_MEAN3 = 704, SF_VAR3 = 832;       // 128 each
constexpr int SF_A4 = 960, SF_BE4 = 1024, SF_BN5 = 1088;
constexpr int SF_SY2 = 1152, SF_SY2Q = 5248;       // 64 banks x 64 ch
constexpr int SF_SY3 = 9344;                       // 1024 banks x 2

#define DEVINL __device__ __forceinline__

DEVINL float wredsum(float v) {
#pragma unroll
  for (int o = 32; o; o >>= 1) v += __shfl_xor(v, o);
  return v;
}

// BN1 (bn_pbt) params from analytic sums.  v = base_n + c_g (+ rare w)
DEVINL void bn1_params(const float* st, const float* g, const float* b, int h,
                       float& a, float& be) {
  float sB = st[SF_SUMB + h], sB2 = st[SF_SUMB2 + h];
  float sC = st[SF_SUMC + h], sC2 = st[SF_SUMC2 + h];
  float mean = (NG * sB + NN * sC + st[SF_CORRV + h]) * (1.0f / MM);
  float e2 = (NG * sB2 + 2.0f * sB * sC + NN * sC2 + st[SF_CORRV2 + h]) * (1.0f / MM);
  float rs = rsqrtf(e2 - mean * mean + EPS);
  a = g[h] * rs;
  be = b[h] - mean * g[h] * rs;
}

// BN2 (bn_pb) params from direct sums of u
DEVINL void bn2_params(const float* st, const float* g, const float* b, int h,
                       float& a, float& be) {
  float m = st[SF_SUMU + h] * (1.0f / MM);
  float var = st[SF_SUMU2 + h] * (1.0f / MM) - m * m;
  float rs = rsqrtf(var + EPS);
  a = g[h] * rs;
  be = b[h] - m * g[h] * rs;
}

// K1: renorm both embeddings (max_norm=1); accumulate gene-emb channel sums
__global__ void k_renorm(const float* __restrict__ ge, const float* __restrict__ pe,
                         float* __restrict__ baseR, float* __restrict__ xg,
                         float* __restrict__ st) {
  __shared__ float red[128];
  if (threadIdx.x < 128) red[threadIdx.x] = 0.f;
  __syncthreads();
  int lane = threadIdx.x & 63;
  int wid = (blockIdx.x * blockDim.x + threadIdx.x) >> 6;
  int nw = (gridDim.x * blockDim.x) >> 6;
  float s1 = 0.f, s2 = 0.f;
  for (int r = wid; r < 2 * NN; r += nw) {
    int gene = r < NN;
    int n = gene ? r : r - NN;
    const float* src = gene ? ge : pe;
    float v = src[n * 64 + lane];
    float sq = wredsum(v * v);
    float nrm = sqrtf(sq);
    float sc = nrm > 1.0f ? 1.0f / (nrm + 1e-7f) : 1.0f;
    v *= sc;
    if (gene) { baseR[n * 64 + lane] = v; s1 += v; s2 += v * v; }
    else      { xg[n * 64 + lane] = v; }
  }
  atomicAdd(&red[lane], s1);
  atomicAdd(&red[64 + lane], s2);
  __syncthreads();
  if (threadIdx.x < 64) {
    atomicAdd(&st[SF_SUME + threadIdx.x], red[threadIdx.x]);
    atomicAdd(&st[SF_SUME2 + threadIdx.x], red[64 + threadIdx.x]);
  }
}

// K0b: transpose rw2_W [64][128] -> W2T [128][64]
__global__ void k_w2t(const float* __restrict__ W2, float* __restrict__ W2T) {
  int i = blockIdx.x * blockDim.x + threadIdx.x;
  if (i < 64 * 128) {
    int r = i >> 7, c = i & 127;
    W2T[c * 64 + r] = W2[i];
  }
}

// K2: base_n = relu(BN_emb(renormed gene emb)); accumulate sumB, sumB2
__global__ void k_base(const float* __restrict__ baseR, const float* __restrict__ g,
                       const float* __restrict__ b, float* __restrict__ base,
                       float* __restrict__ st) {
  __shared__ float red[128];
  if (threadIdx.x < 128) red[threadIdx.x] = 0.f;
  __syncthreads();
  int h = threadIdx.x & 63;
  float m = st[SF_SUME + h] * (1.0f / NN);
  float var = st[SF_SUME2 + h] * (1.0f / NN) - m * m;
  float rs = rsqrtf(var + EPS);
  float a = g[h] * rs, be = b[h] - m * g[h] * rs;
  float s1 = 0.f, s2 = 0.f;
  int stride = gridDim.x * blockDim.x;
  for (int i = blockIdx.x * blockDim.x + threadIdx.x; i < NN * 64; i += stride) {
    float v = fmaxf(baseR[i] * a + be, 0.f);
    base[i] = v; s1 += v; s2 += v * v;
  }
  atomicAdd(&red[h], s1);
  atomicAdd(&red[64 + h], s2);
  __syncthreads();
  if (threadIdx.x < 64) {
    atomicAdd(&st[SF_SUMB + threadIdx.x], red[threadIdx.x]);
    atomicAdd(&st[SF_SUMB2 + threadIdx.x], red[64 + threadIdx.x]);
  }
}

// K3: degree (segment_sum of w by col, + self loops)
__global__ void k_deg(const int* __restrict__ ei, const float* __restrict__ ew,
                      float* __restrict__ deg) {
  int i = blockIdx.x * blockDim.x + threadIdx.x;
  if (i < NE) atomicAdd(&deg[ei[NE + i]], ew[i]);
  else if (i < NE + NN) atomicAdd(&deg[i - NE], 1.0f);
}

// K4: agg[col] += dinv[row]*w*dinv[col] * xg[row]  (one wave per edge)
__global__ void k_agg(const int* __restrict__ ei, const float* __restrict__ ew,
                      const float* __restrict__ deg, const float* __restrict__ xg,
                      float* __restrict__ agg) {
  int w = (blockIdx.x * blockDim.x + threadIdx.x) >> 6;
  int lane = threadIdx.x & 63;
  if (w < NE) {
    int r = ei[w], c = ei[NE + w];
    float dr = deg[r], dc = deg[c];
    float nrm = ew[w] * (dr > 0.f ? rsqrtf(dr) : 0.f) * (dc > 0.f ? rsqrtf(dc) : 0.f);
    atomicAdd(&agg[c * 64 + lane], nrm * xg[r * 64 + lane]);
  } else if (w < NE + NN) {
    int n = w - NE;
    float d = deg[n];
    float nrm = d > 0.f ? 1.0f / d : 0.f;   // dinv * 1 * dinv
    atomicAdd(&agg[n * 64 + lane], nrm * xg[n * 64 + lane]);
  }
}

// K5: pge = agg @ sgW.T + sgb  (lane j holds W row j in regs; agg via shfl)
__global__ void k_pge(const float* __restrict__ agg, const float* __restrict__ W,
                      const float* __restrict__ bb, float* __restrict__ pge) {
  int lane = threadIdx.x & 63;
  int wid = (blockIdx.x * blockDim.x + threadIdx.x) >> 6;
  int nw = (gridDim.x * blockDim.x) >> 6;
  float wr[64];
#pragma unroll
  for (int k4 = 0; k4 < 16; k4++) {
    float4 t = *(const float4*)&W[lane * 64 + k4 * 4];
    wr[k4 * 4] = t.x; wr[k4 * 4 + 1] = t.y; wr[k4 * 4 + 2] = t.z; wr[k4 * 4 + 3] = t.w;
  }
  float bj = bb[lane];
  for (int n = wid; n < NN; n += nw) {
    float av = agg[n * 64 + lane];
    float acc = bj;
#pragma unroll
    for (int k = 0; k < 64; k++) acc += __shfl(av, k) * wr[k];
    pge[n * 64 + lane] = acc;
  }
}

// K6: find perturbed genes from x[:,1]
__global__ void k_extract(const float* __restrict__ x, int* __restrict__ pcnt,
                          int* __restrict__ pgene) {
  int r = blockIdx.x * blockDim.x + threadIdx.x;
  if (r < MM) {
    float v = x[(size_t)2 * r + 1];
    if (v != 0.0f) {
      int g = r >> 13;
      int slot = atomicAdd(&pcnt[g], 1);
      if (slot < 2) pgene[g * 2 + slot] = r & (NN - 1);
    }
  }
}

// K7: c_g = LAM * sum(pge[pert]) + pert_b; accumulate sumC, sumC2
__global__ void k_cg(const float* __restrict__ pge, const float* __restrict__ pb,
                     const int* __restrict__ pcnt, const int* __restrict__ pgene,
                     float* __restrict__ cg, float* __restrict__ st) {
  int g = blockIdx.x, h = threadIdx.x;
  float c = pb[h];
  int cnt = pcnt[g]; if (cnt > 2) cnt = 2;
  for (int i = 0; i < cnt; i++) c += LAM * pge[pgene[g * 2 + i] * 64 + h];
  cg[g * 64 + h] = c;
  atomicAdd(&st[SF_SUMC + h], c);
  atomicAdd(&st[SF_SUMC2 + h], c * c);
}

// K7b (parallel): BN1 corrections, one block per pert entry
__global__ void k_corr1p(const float* __restrict__ base, const float* __restrict__ cg,
                         const float* __restrict__ pw, const int* __restrict__ pcnt,
                         const int* __restrict__ pgene, float* __restrict__ st) {
  int e = blockIdx.x, g = e >> 1, slot = e & 1;
  int cnt = pcnt[g]; if (cnt > 2) cnt = 2;
  if (slot >= cnt) return;
  int row = pgene[g * 2 + slot];
  int h = threadIdx.x;
  float w = pw[h];
  float v0 = base[row * 64 + h] + cg[g * 64 + h];
  atomicAdd(&st[SF_CORRV + h], w);
  atomicAdd(&st[SF_CORRV2 + h], 2.f * v0 * w + w * w);
}

// K8: BN2 stats: u = relu(BN1(base_n + c_g)) summed over all (g,n)
__global__ void k_ustats(const float* __restrict__ base, const float* __restrict__ cg,
                         const float* __restrict__ g1, const float* __restrict__ b1,
                         float* __restrict__ st) {
  __shared__ float red[128];
  if (threadIdx.x < 128) red[threadIdx.x] = 0.f;
  __syncthreads();
  int h = threadIdx.x & 63;
  int g = blockIdx.x >> 3;
  int n0 = (blockIdx.x & 7) * 1024;
  float a1, be1; bn1_params(st, g1, b1, h, a1, be1);
  float ch = cg[g * 64 + h];
  float s1 = 0.f, s2 = 0.f;
  for (int r = n0 + (threadIdx.x >> 6); r < n0 + 1024; r += 4) {
    float u = fmaxf(a1 * (base[r * 64 + h] + ch) + be1, 0.f);
    s1 += u; s2 += u * u;
  }
  atomicAdd(&red[h], s1);
  atomicAdd(&red[64 + h], s2);
  __syncthreads();
  if (threadIdx.x < 64) {
    atomicAdd(&st[SF_SUMU + threadIdx.x], red[threadIdx.x]);
    atomicAdd(&st[SF_SUMU2 + threadIdx.x], red[64 + threadIdx.x]);
  }
}

// K8b (parallel): BN2 stat corrections, one block per pert entry
__global__ void k_ucorrp(const float* __restrict__ base, const float* __restrict__ cg,
                         const float* __restrict__ pw, const int* __restrict__ pcnt,
                         const int* __restrict__ pgene, const float* __restrict__ g1,
                         const float* __restrict__ b1, float* __restrict__ st) {
  int e = blockIdx.x, g = e >> 1, slot = e & 1;
  int cnt = pcnt[g]; if (cnt > 2) cnt = 2;
  if (slot >= cnt) return;
  int row = pgene[g * 2 + slot];
  int h = threadIdx.x;
  float a1, be1; bn1_params(st, g1, b1, h, a1, be1);
  float w = pw[h];
  float v0 = base[row * 64 + h] + cg[g * 64 + h];
  float u0 = fmaxf(a1 * v0 + be1, 0.f);
  float uw = fmaxf(a1 * (v0 + w) + be1, 0.f);
  atomicAdd(&st[SF_SUMU + h], uw - u0);
  atomicAdd(&st[SF_SUMU2 + h], uw * uw - u0 * u0);
}

// K9: Gram of t = relu(BN2(relu(BN1(base+c)))), plus sumT
__global__ void k_gram(const float* __restrict__ base, const float* __restrict__ cg,
                       const float* __restrict__ g1, const float* __restrict__ b1,
                       const float* __restrict__ g2, const float* __restrict__ b2,
                       float* __restrict__ G, float* __restrict__ st) {
  __shared__ __align__(16) float tS[16][68];
  __shared__ float red[128];
  if (threadIdx.x < 128) red[threadIdx.x] = 0.f;
  int h = threadIdx.x & 63;
  int g = blockIdx.x >> 3;
  int n0 = (blockIdx.x & 7) * 1024;
  float a1, be1, a2, be2;
  bn1_params(st, g1, b1, h, a1, be1);
  bn2_params(st, g2, b2, h, a2, be2);
  float ch = cg[g * 64 + h];
  int i0 = (threadIdx.x >> 4) * 4;
  int j0 = (threadIdx.x & 15) * 4;
  float acc[4][4] = {};
  float sT = 0.f;
  for (int nb = 0; nb < 1024; nb += 16) {
    __syncthreads();
#pragma unroll
    for (int it = 0; it < 4; it++) {
      int r = it * 4 + (threadIdx.x >> 6);
      float v = base[(n0 + nb + r) * 64 + h] + ch;
      float t = fmaxf(a2 * fmaxf(a1 * v + be1, 0.f) + be2, 0.f);
      tS[r][h] = t;
      sT += t;
    }
    __syncthreads();
#pragma unroll
    for (int r = 0; r < 16; r++) {
      float4 a4 = *(const float4*)&tS[r][i0];
      float4 b4 = *(const float4*)&tS[r][j0];
      float ai[4] = {a4.x, a4.y, a4.z, a4.w};
      float bj[4] = {b4.x, b4.y, b4.z, b4.w};
#pragma unroll
      for (int a = 0; a < 4; a++)
#pragma unroll
        for (int b = 0; b < 4; b++) acc[a][b] += ai[a] * bj[b];
    }
  }
#pragma unroll
  for (int a = 0; a < 4; a++)
#pragma unroll
    for (int b = 0; b < 4; b++)
      atomicAdd(&G[(i0 + a) * 64 + j0 + b], acc[a][b]);
  atomicAdd(&red[h], sT);
  __syncthreads();
  if (threadIdx.x < 64) atomicAdd(&st[SF_SUMT + threadIdx.x], red[threadIdx.x]);
}

// K9b (parallel): Gram + sumT corrections, one block per pert entry
__global__ void k_gramcorrp(const float* __restrict__ base, const float* __restrict__ cg,
                            const float* __restrict__ pw, const int* __restrict__ pcnt,
                            const int* __restrict__ pgene,
                            const float* __restrict__ g1, const float* __restrict__ b1,
                            const float* __restrict__ g2, const float* __restrict__ b2,
                            float* __restrict__ G, float* __restrict__ st) {
  __shared__ float t0S[64], twS[64];
  int e = blockIdx.x, g = e >> 1, slot = e & 1;
  int cnt = pcnt[g]; if (cnt > 2) cnt = 2;
  if (slot >= cnt) return;
  int row = pgene[g * 2 + slot];
  int tid = threadIdx.x;
  if (tid < 64) {
    float a1, be1, a2, be2;
    bn1_params(st, g1, b1, tid, a1, be1);
    bn2_params(st, g2, b2, tid, a2, be2);
    float v0 = base[row * 64 + tid] + cg[g * 64 + tid];
    float t0 = fmaxf(a2 * fmaxf(a1 * v0 + be1, 0.f) + be2, 0.f);
    float tw = fmaxf(a2 * fmaxf(a1 * (v0 + pw[tid]) + be1, 0.f) + be2, 0.f);
    t0S[tid] = t0; twS[tid] = tw;
    atomicAdd(&st[SF_SUMT + tid], tw - t0);
  }
  __syncthreads();
  int i0 = (tid >> 4) * 4;
  int j0 = (tid & 15) * 4;
#pragma unroll
  for (int a = 0; a < 4; a++)
#pragma unroll
    for (int b = 0; b < 4; b++)
      atomicAdd(&G[(i0 + a) * 64 + j0 + b],
                twS[i0 + a] * twS[j0 + b] - t0S[i0 + a] * t0S[j0 + b]);
}

// K9c: BN3 stats from Gram: y1_j = w_j.t + b1_j
__global__ void k_bn3(const float* __restrict__ W1, const float* __restrict__ b1v,
                      const float* __restrict__ G, float* __restrict__ st) {
  int j = blockIdx.x, h = threadIdx.x;
  float wjh = W1[j * 64 + h];
  float inner = 0.f;
  for (int l = 0; l < 64; l++) inner += G[h * 64 + l] * W1[j * 64 + l];
  float q = wredsum(wjh * inner);
  float s = wredsum(wjh * st[SF_SUMT + h]);
  if (h == 0) {
    float bj = b1v[j];
    float mu = s * (1.0f / MM) + bj;
    float e2 = q * (1.0f / MM) + 2.0f * bj * s * (1.0f / MM) + bj * bj;
    st[SF_MEAN3 + j] = mu;
    st[SF_VAR3 + j] = e2 - mu * mu;
  }
}

// K10: fused MLP pass, restructured for occupancy + conflict-free LDS.
// t stored row-major [r][k] (write lane-contiguous). h1 never hits a big LDS
// buffer: GEMM2 consumes h1 via a 3KB double-buffered 4-j stage tile.
// MODE 0: store y2 + BN4 stat sums.  MODE 1: stats only.  MODE 2: final y3.
template <int MODE>
__launch_bounds__(128, 4)
__global__ void k_mlp(const float* __restrict__ x, const float* __restrict__ base,
                      const float* __restrict__ cg, const float* __restrict__ pw,
                      const float* __restrict__ g1, const float* __restrict__ b1,
                      const float* __restrict__ g2, const float* __restrict__ b2,
                      const float* __restrict__ W1, const float* __restrict__ b1v,
                      const float* __restrict__ g3, const float* __restrict__ b3,
                      const float* __restrict__ W2T, const float* __restrict__ b2v,
                      const float* __restrict__ w3, const float* __restrict__ b3v,
                      float* __restrict__ st, float* __restrict__ y2out,
                      float* __restrict__ y3out) {
  __shared__ __align__(16) float tT2[64][68];   // [row][k], stride 68 (16B-aligned)
  __shared__ float stg[2][64 * 6];              // stage: [row][4 j] stride 6 words
  __shared__ float cS[64];
  __shared__ float x1S[64];
  __shared__ float red[128];
  int tid = threadIdx.x;
  int g = blockIdx.x >> 7;
  int n0 = (blockIdx.x & 127) * 64;
  int k = tid & 63;
  float a1, be1, a2, be2;
  bn1_params(st, g1, b1, k, a1, be1);
  bn2_params(st, g2, b2, k, a2, be2);
  if (tid < 64) cS[tid] = cg[g * 64 + tid];
  else {
    int r = tid - 64;
    x1S[r] = x[((size_t)(g * NN + n0 + r)) * 2 + 1];
  }
  if (tid < 128) red[tid] = 0.f;
  __syncthreads();
  float pwk = pw[k];
  float chk = cS[k];
  // fill t row-major: lane k writes word r*68+k -> stride-1 across lanes, no conflict
#pragma unroll
  for (int it = 0; it < 32; it++) {
    int r = it * 2 + (tid >> 6);
    float v = base[(n0 + r) * 64 + k] + chk + x1S[r] * pwk;
    float t = fmaxf(a2 * fmaxf(a1 * v + be1, 0.f) + be2, 0.f);
    tT2[r][k] = t;
  }
  __syncthreads();

  int rg = tid >> 4;         // 0..7
  int r0 = rg * 8;
  int m = tid & 15;
  int i0 = m * 4;
  float y2acc[8][4] = {};

  for (int jp = 0; jp < 2; jp++) {
    // ---- GEMM1 half: y1[64 rows][64 j], thread tile 8r x 4j ----
    int j0g = jp * 64 + m * 4;
    float acc[8][4] = {};
    for (int kc = 0; kc < 64; kc += 4) {
      float w1s[4][4];
#pragma unroll
      for (int jj = 0; jj < 4; jj++) {
        float4 t4 = *(const float4*)&W1[(j0g + jj) * 64 + kc];
        w1s[jj][0] = t4.x; w1s[jj][1] = t4.y; w1s[jj][2] = t4.z; w1s[jj][3] = t4.w;
      }
#pragma unroll
      for (int rr = 0; rr < 8; rr++) {
        float4 t4 = *(const float4*)&tT2[r0 + rr][kc];
#pragma unroll
        for (int jj = 0; jj < 4; jj++)
          acc[rr][jj] += t4.x * w1s[jj][0] + t4.y * w1s[jj][1] +
                         t4.z * w1s[jj][2] + t4.w * w1s[jj][3];
      }
    }
    // h1 = relu(BN3(y1 + b1)) kept in registers
    float hreg[8][4];
#pragma unroll
    for (int jj = 0; jj < 4; jj++) {
      int j = j0g + jj;
      float mu = st[SF_MEAN3 + j], va = st[SF_VAR3 + j];
      float rs = rsqrtf(va + EPS);
      float a3 = g3[j] * rs, be3 = b3[j] - mu * a3;
      float bj = b1v[j];
#pragma unroll
      for (int rr = 0; rr < 8; rr++)
        hreg[rr][jj] = fmaxf(a3 * (acc[rr][jj] + bj) + be3, 0.f);
    }
    // ---- GEMM2 half via staged 4-j tiles (double-buffered, 1 barrier/iter) ----
    if (m == 0) {
#pragma unroll
      for (int rr = 0; rr < 8; rr++) {
        *(float2*)&stg[0][(r0 + rr) * 6 + 0] = make_float2(hreg[rr][0], hreg[rr][1]);
        *(float2*)&stg[0][(r0 + rr) * 6 + 2] = make_float2(hreg[rr][2], hreg[rr][3]);
      }
    }
    __syncthreads();
    for (int mi = 0; mi < 16; mi++) {
      int buf = mi & 1;
      if (mi < 15 && m == mi + 1) {
#pragma unroll
        for (int rr = 0; rr < 8; rr++) {
          *(float2*)&stg[buf ^ 1][(r0 + rr) * 6 + 0] = make_float2(hreg[rr][0], hreg[rr][1]);
          *(float2*)&stg[buf ^ 1][(r0 + rr) * 6 + 2] = make_float2(hreg[rr][2], hreg[rr][3]);
        }
      }
      float w2s[4][4];
#pragma unroll
      for (int jj = 0; jj < 4; jj++) {
        float4 t4 = *(const float4*)&W2T[(jp * 64 + mi * 4 + jj) * 64 + i0];
        w2s[jj][0] = t4.x; w2s[jj][1] = t4.y; w2s[jj][2] = t4.z; w2s[jj][3] = t4.w;
      }
#pragma unroll
      for (int rr = 0; rr < 8; rr++) {
        float2 ha = *(const float2*)&stg[buf][(r0 + rr) * 6 + 0];
        float2 hb = *(const float2*)&stg[buf][(r0 + rr) * 6 + 2];
        float hv[4] = {ha.x, ha.y, hb.x, hb.y};
#pragma unroll
        for (int jj = 0; jj < 4; jj++)
#pragma unroll
          for (int ii = 0; ii < 4; ii++)
            y2acc[rr][ii] += hv[jj] * w2s[jj][ii];
      }
      __syncthreads();
    }
  }

  float bi[4];
#pragma unroll
  for (int ii = 0; ii < 4; ii++) bi[ii] = b2v[i0 + ii];
#pragma unroll
  for (int rr = 0; rr < 8; rr++)
#pragma unroll
    for (int ii = 0; ii < 4; ii++) y2acc[rr][ii] += bi[ii];

  if (MODE == 0) {
#pragma unroll
    for (int rr = 0; rr < 8; rr++) {
      size_t row = (size_t)(g * NN + n0 + r0 + rr);
      *(float4*)&y2out[row * 64 + i0] =
          make_float4(y2acc[rr][0], y2acc[rr][1], y2acc[rr][2], y2acc[rr][3]);
    }
  }
  if (MODE <= 1) {
    float s1[4] = {}, s2[4] = {};
#pragma unroll
    for (int rr = 0; rr < 8; rr++)
#pragma unroll
      for (int ii = 0; ii < 4; ii++) {
        s1[ii] += y2acc[rr][ii];
        s2[ii] += y2acc[rr][ii] * y2acc[rr][ii];
      }
#pragma unroll
    for (int ii = 0; ii < 4; ii++) {
      atomicAdd(&red[i0 + ii], s1[ii]);
      atomicAdd(&red[64 + i0 + ii], s2[ii]);
    }
    __syncthreads();
    if (tid < 64) {
      int bank = blockIdx.x & 63;
      atomicAdd(&st[SF_SY2 + bank * 64 + tid], red[tid]);
      atomicAdd(&st[SF_SY2Q + bank * 64 + tid], red[64 + tid]);
    }
  }
  if (MODE == 2) {
    float a4v[4], be4v[4], w3v[4];
#pragma unroll
    for (int ii = 0; ii < 4; ii++) {
      a4v[ii] = st[SF_A4 + i0 + ii];
      be4v[ii] = st[SF_BE4 + i0 + ii];
      w3v[ii] = w3[i0 + ii];
    }
#pragma unroll
    for (int rr = 0; rr < 8; rr++) {
      float part = 0.f;
#pragma unroll
      for (int ii = 0; ii < 4; ii++) {
        float h2 = fmaxf(a4v[ii] * y2acc[rr][ii] + be4v[ii], 0.f);
        part += w3v[ii] * h2;
      }
      atomicAdd(&red[r0 + rr], part);
    }
    __syncthreads();
    if (tid < 64) {
      float yv = red[tid] + b3v[0];
      y3out[(size_t)(g * NN + n0 + tid)] = yv;
      float q1 = wredsum(yv);
      float q2 = wredsum(yv * yv);
      if (tid == 0) {
        int bank = blockIdx.x & 1023;
        atomicAdd(&st[SF_SY3 + bank * 2], q1);
        atomicAdd(&st[SF_SY3 + bank * 2 + 1], q2);
      }
    }
  }
}

// K11: finalize BN4 params from banked sums
__global__ void k_bn4fin(const float* __restrict__ g4, const float* __restrict__ b4,
                         float* __restrict__ st) {
  int h = threadIdx.x;
  float s1 = 0.f, s2 = 0.f;
  for (int b = 0; b < 64; b++) {
    s1 += st[SF_SY2 + b * 64 + h];
    s2 += st[SF_SY2Q + b * 64 + h];
  }
  float m = s1 * (1.0f / MM);
  float var = s2 * (1.0f / MM) - m * m;
  float rs = rsqrtf(var + EPS);
  st[SF_A4 + h] = g4[h] * rs;
  st[SF_BE4 + h] = b4[h] - m * g4[h] * rs;
}

// K12 (store path): read y2, apply BN4+relu, dot w3 -> y3 + BN5 sums
__global__ void k_fin_read(const float* __restrict__ y2g, const float* __restrict__ w3,
                           const float* __restrict__ b3v, float* __restrict__ st,
                           float* __restrict__ y3) {
  int lane = threadIdx.x & 63;
  float a4 = st[SF_A4 + lane], be4 = st[SF_BE4 + lane], w = w3[lane];
  int wid = (blockIdx.x * blockDim.x + threadIdx.x) >> 6;
  int nw = (gridDim.x * blockDim.x) >> 6;
  float q1 = 0.f, q2 = 0.f;
  for (int r = wid; r < MM; r += nw) {
    float v = y2g[(size_t)r * 64 + lane];
    float p = wredsum(w * fmaxf(a4 * v + be4, 0.f));
    if (lane == 0) {
      float yv = p + b3v[0];
      y3[r] = yv;
      q1 += yv; q2 += yv * yv;
    }
  }
  if (lane == 0) {
    int bank = (blockIdx.x * 4 + (threadIdx.x >> 6)) & 1023;
    atomicAdd(&st[SF_SY3 + bank * 2], q1);
    atomicAdd(&st[SF_SY3 + bank * 2 + 1], q2);
  }
}

// K12b: finalize BN5
__global__ void k_bn5fin(const float* __restrict__ g5, const float* __restrict__ b5,
                         float* __restrict__ st) {
  int t = threadIdx.x;
  float s1 = 0.f, s2 = 0.f;
  for (int b = t; b < 1024; b += 64) {
    s1 += st[SF_SY3 + b * 2];
    s2 += st[SF_SY3 + b * 2 + 1];
  }
  s1 = wredsum(s1);
  s2 = wredsum(s2);
  if (t == 0) {
    float m = s1 * (1.0f / MM);
    float var = s2 * (1.0f / MM) - m * m;
    float rs = rsqrtf(var + EPS);
    st[SF_BN5] = g5[0] * rs;
    st[SF_BN5 + 1] = b5[0] - m * g5[0] * rs;
  }
}

// K13: out = BN5(y3) + x[:,0]
__global__ void k_out(const float* __restrict__ y3, const float* __restrict__ x,
                      const float* __restrict__ st, float* __restrict__ out) {
  int i = blockIdx.x * blockDim.x + threadIdx.x;
  float sc = st[SF_BN5], sh = st[SF_BN5 + 1];
  if (i < MM) out[i] = y3[i] * sc + sh + x[(size_t)i * 2];
}

extern "C" void kernel_launch(void* const* d_in, const int* in_sizes, int n_in,
                              void* d_out, int out_size, void* d_ws, size_t ws_size,
                              hipStream_t stream) {
  const float* x   = (const float*)d_in[0];
  const int*   ei  = (const int*)d_in[1];
  const float* ew  = (const float*)d_in[2];
  const float* ge  = (const float*)d_in[3];
  const float* pe  = (const float*)d_in[4];
  const float* pW  = (const float*)d_in[5];
  const float* pb  = (const float*)d_in[6];
  const float* sgW = (const float*)d_in[7];
  const float* sgb = (const float*)d_in[8];
  const float* beg = (const float*)d_in[9],  *beb = (const float*)d_in[10];
  const float* g1  = (const float*)d_in[11], *b1  = (const float*)d_in[12];
  const float* g2  = (const float*)d_in[13], *b2  = (const float*)d_in[14];
  const float* W1  = (const float*)d_in[15], *b1v = (const float*)d_in[16];
  const float* g3  = (const float*)d_in[17], *b3  = (const float*)d_in[18];
  const float* W2  = (const float*)d_in[19], *b2v = (const float*)d_in[20];
  const float* g4  = (const float*)d_in[21], *b4  = (const float*)d_in[22];
  const float* w3  = (const float*)d_in[23], *b3v = (const float*)d_in[24];
  const float* g5  = (const float*)d_in[25], *b5  = (const float*)d_in[26];
  float* out = (float*)d_out;
  char* ws = (char*)d_ws;
  float* st    = (float*)(ws + WO_STATS);
  int*   pcnt  = (int*)(ws + WO_INTS);
  int*   pgene = pcnt + 64;
  float* deg   = (float*)(ws + WO_DEG);
  float* G     = (float*)(ws + WO_G);
  float* agg   = (float*)(ws + WO_AGG);
  float* cgp   = (float*)(ws + WO_CG);
  float* W2T   = (float*)(ws + WO_W2T);
  float* baseR = (float*)(ws + WO_BASER);
  float* base  = (float*)(ws + WO_BASE);
  float* xg    = (float*)(ws + WO_XG);
  float* pge   = (float*)(ws + WO_PGE);
  float* y3    = (float*)(ws + WO_Y3);
  float* y2    = (float*)(ws + WO_Y2);
  bool store = ws_size >= WO_Y2 + (size_t)MM * 64 * 4;

  hipMemsetAsync(d_ws, 0, ZERO_BYTES, stream);
  hipLaunchKernelGGL(k_renorm, dim3(256), dim3(256), 0, stream, ge, pe, baseR, xg, st);
  hipLaunchKernelGGL(k_w2t, dim3(32), dim3(256), 0, stream, W2, W2T);
  hipLaunchKernelGGL(k_base, dim3(512), dim3(256), 0, stream, baseR, beg, beb, base, st);
  hipLaunchKernelGGL(k_deg, dim3((NE + NN + 255) / 256), dim3(256), 0, stream, ei, ew, deg);
  hipLaunchKernelGGL(k_agg, dim3((NE + NN) / 4), dim3(256), 0, stream, ei, ew, deg, xg, agg);
  hipLaunchKernelGGL(k_pge, dim3(512), dim3(256), 0, stream, agg, sgW, sgb, pge);
  hipLaunchKernelGGL(k_extract, dim3(MM / 256), dim3(256), 0, stream, x, pcnt, pgene);
  hipLaunchKernelGGL(k_cg, dim3(64), dim3(64), 0, stream, pge, pb, pcnt, pgene, cgp, st);
  hipLaunchKernelGGL(k_corr1p, dim3(128), dim3(64), 0, stream, base, cgp, pW, pcnt, pgene, st);
  hipLaunchKernelGGL(k_ustats, dim3(512), dim3(256), 0, stream, base, cgp, g1, b1, st);
  hipLaunchKernelGGL(k_ucorrp, dim3(128), dim3(64), 0, stream, base, cgp, pW, pcnt, pgene, g1, b1, st);
  hipLaunchKernelGGL(k_gram, dim3(512), dim3(256), 0, stream, base, cgp, g1, b1, g2, b2, G, st);
  hipLaunchKernelGGL(k_gramcorrp, dim3(128), dim3(256), 0, stream, base, cgp, pW, pcnt, pgene,
                     g1, b1, g2, b2, G, st);
  hipLaunchKernelGGL(k_bn3, dim3(128), dim3(64), 0, stream, W1, b1v, G, st);
  if (store) {
    hipLaunchKernelGGL(k_mlp<0>, dim3(8192), dim3(128), 0, stream,
                       x, base, cgp, pW, g1, b1, g2, b2, W1, b1v, g3, b3, W2T, b2v,
                       w3, b3v, st, y2, y3);
    hipLaunchKernelGGL(k_bn4fin, dim3(1), dim3(64), 0, stream, g4, b4, st);
    hipLaunchKernelGGL(k_fin_read, dim3(4096), dim3(256), 0, stream, y2, w3, b3v, st, y3);
  } else {
    hipLaunchKernelGGL(k_mlp<1>, dim3(8192), dim3(128), 0, stream,
                       x, base, cgp, pW, g1, b1, g2, b2, W1, b1v, g3, b3, W2T, b2v,
                       w3, b3v, st, y2, y3);
    hipLaunchKernelGGL(k_bn4fin, dim3(1), dim3(64), 0, stream, g4, b4, st);
    hipLaunchKernelGGL(k_mlp<2>, dim3(8192), dim3(128), 0, stream,
                       x, base, cgp, pW, g1, b1, g2, b2, W1, b1v, g3, b3, W2T, b2v,
                       w3, b3v, st, y2, y3);
  }
  hipLaunchKernelGGL(k_bn5fin, dim3(1), dim3(64), 0, stream, g5, b5, st);
  hipLaunchKernelGGL(k_out, dim3(MM / 256), dim3(256), 0, stream, y3, x, st, out);
}